// Round 3
// baseline (1571.957 us; speedup 1.0000x reference)
//
#include <hip/hip_runtime.h>
#include <hip/hip_bf16.h>

typedef unsigned short u16;
typedef __bf16 bf16x8 __attribute__((ext_vector_type(8)));
typedef float f32x4 __attribute__((ext_vector_type(4)));

__device__ inline u16 f2b(float f) {
    __hip_bfloat16 h = __float2bfloat16(f);
    return *(u16*)&h;
}

#define BM 128
#define BN 128
#define BK 32
#define LDSS 40  // 32 + 8 pad shorts per row

// C[M,N] = A[M,K] * W[N,K]^T.  W is bf16 (pre-converted), row-major K-contiguous.
// A: AF32=1 -> float32 (converted to bf16 during LDS staging), AF32=0 -> bf16.
// EPI: 0 = store f32, 1 = silu -> bf16
template<int AF32, int EPI>
__global__ __launch_bounds__(256) void gemm_bt(const void* __restrict__ Av,
                                               const u16* __restrict__ W,
                                               void* __restrict__ Cv,
                                               int M, int N, int K) {
    __shared__ u16 lds_a[BM * LDSS];
    __shared__ u16 lds_b[BN * LDSS];
    const int tid  = threadIdx.x;
    const int wave = tid >> 6;
    const int lane = tid & 63;
    const int wr = wave >> 1, wc = wave & 1;   // 2x2 wave grid, 64x64 each
    const int quad = lane >> 4, l15 = lane & 15;
    const int bm = blockIdx.x * BM;
    const int bn = blockIdx.y * BN;

    f32x4 acc[4][4] = {};

    const int lrow = tid >> 2;    // 0..63
    const int lch  = tid & 3;     // 16B chunk within 32-k bf16 row

    for (int k0 = 0; k0 < K; k0 += BK) {
        __syncthreads();
        if (AF32) {
            const float* Af = (const float*)Av;
            const int srow = tid >> 3;   // 0..31
            const int sch  = tid & 7;    // float4 chunk within 32-k f32 row
            #pragma unroll
            for (int p = 0; p < 4; ++p) {
                const int r = p * 32 + srow;
                float4 va = *(const float4*)&Af[(size_t)(bm + r) * K + k0 + sch * 4];
                ushort4 pk = make_ushort4(f2b(va.x), f2b(va.y), f2b(va.z), f2b(va.w));
                *(ushort4*)&lds_a[r * LDSS + sch * 4] = pk;
            }
        } else {
            const u16* Ab = (const u16*)Av;
            *(uint4*)&lds_a[lrow * LDSS + lch * 8] =
                *(const uint4*)&Ab[(size_t)(bm + lrow) * K + k0 + lch * 8];
            *(uint4*)&lds_a[(lrow + 64) * LDSS + lch * 8] =
                *(const uint4*)&Ab[(size_t)(bm + lrow + 64) * K + k0 + lch * 8];
        }
        *(uint4*)&lds_b[lrow * LDSS + lch * 8] =
            *(const uint4*)&W[(size_t)(bn + lrow) * K + k0 + lch * 8];
        *(uint4*)&lds_b[(lrow + 64) * LDSS + lch * 8] =
            *(const uint4*)&W[(size_t)(bn + lrow + 64) * K + k0 + lch * 8];
        __syncthreads();

        bf16x8 af[4], bf[4];
        #pragma unroll
        for (int i = 0; i < 4; i++)
            af[i] = *(const bf16x8*)&lds_a[(wr * 64 + i * 16 + l15) * LDSS + quad * 8];
        #pragma unroll
        for (int j = 0; j < 4; j++)
            bf[j] = *(const bf16x8*)&lds_b[(wc * 64 + j * 16 + l15) * LDSS + quad * 8];
        #pragma unroll
        for (int i = 0; i < 4; i++)
            #pragma unroll
            for (int j = 0; j < 4; j++)
                acc[i][j] = __builtin_amdgcn_mfma_f32_16x16x32_bf16(af[i], bf[j], acc[i][j], 0, 0, 0);
    }

    #pragma unroll
    for (int i = 0; i < 4; i++) {
        #pragma unroll
        for (int j = 0; j < 4; j++) {
            #pragma unroll
            for (int r = 0; r < 4; r++) {
                const int row = bm + wr * 64 + i * 16 + quad * 4 + r;
                const int col = bn + wc * 64 + j * 16 + l15;
                float v = acc[i][j][r];
                if (EPI == 1) {
                    v = v / (1.f + __expf(-v));   // silu
                    ((__hip_bfloat16*)Cv)[(size_t)row * N + col] = __float2bfloat16(v);
                } else {
                    ((float*)Cv)[(size_t)row * N + col] = v;
                }
            }
        }
    }
}

// Convert all weights f32 -> bf16: W_in [1024x1024], concat(W_k,W_v,W_q,W_a) [256x1024], W_out [1024x64]
__global__ __launch_bounds__(256) void convert_w(const float* __restrict__ Win,
                                                 const float* __restrict__ Wk,
                                                 const float* __restrict__ Wv,
                                                 const float* __restrict__ Wq,
                                                 const float* __restrict__ Wa,
                                                 const float* __restrict__ Wout,
                                                 u16* __restrict__ Win16,
                                                 u16* __restrict__ Wc16,
                                                 u16* __restrict__ Wout16) {
    int idx = blockIdx.x * 256 + threadIdx.x;   // 0 .. 1376255
    if (idx < 1048576) { Win16[idx] = f2b(Win[idx]); return; }
    int i2 = idx - 1048576;
    if (i2 < 262144) {
        int which = i2 >> 16;
        int off = i2 & 65535;
        const float* s = (which == 0) ? Wk : (which == 1) ? Wv : (which == 2) ? Wq : Wa;
        Wc16[i2] = f2b(s[off]);
        return;
    }
    int i3 = i2 - 262144;
    Wout16[i3] = f2b(Wout[i3]);
}

#define T_LEN 2048
#define NS 64

// One block per batch. 256 threads: i = tid&63 (state row), g = tid>>6 (16-col group).
__global__ __launch_bounds__(256) void scan_kernel(const float* __restrict__ P,
                                                   const float* __restrict__ d_alpha,
                                                   const float* __restrict__ b_alpha,
                                                   __hip_bfloat16* __restrict__ cell,
                                                   float* __restrict__ Sout) {
    const int b = blockIdx.x;
    const int tid = threadIdx.x;
    const int i = tid & 63;
    const int g = tid >> 6;

    __shared__ float rowbuf[2][1024];   // 4 P-rows (k|v|q|ax each 64) per buffer
    __shared__ float part_r[4][64];
    __shared__ float part_o[4][64];

    float s[16];
    #pragma unroll
    for (int jj = 0; jj < 16; jj++) s[jj] = 0.f;

    const float da = d_alpha[i];
    const float ba = b_alpha[i];

    const float* Pb = P + (size_t)b * T_LEN * 256;
    float4 pend = *(const float4*)&Pb[tid * 4];

    for (int c = 0; c < 512; ++c) {
        const int buf = c & 1;
        *(float4*)&rowbuf[buf][tid * 4] = pend;
        __syncthreads();
        if (c + 1 < 512) pend = *(const float4*)&Pb[(size_t)(c + 1) * 1024 + tid * 4];

        #pragma unroll
        for (int sub = 0; sub < 4; ++sub) {
            const int t = c * 4 + sub;
            const float* row = &rowbuf[buf][sub * 256];
            float r0 = 0.f, r1 = 0.f, r2 = 0.f, r3 = 0.f;
            #pragma unroll
            for (int jj = 0; jj < 16; jj += 4) {
                r0 += s[jj]     * row[g * 16 + jj];
                r1 += s[jj + 1] * row[g * 16 + jj + 1];
                r2 += s[jj + 2] * row[g * 16 + jj + 2];
                r3 += s[jj + 3] * row[g * 16 + jj + 3];
            }
            part_r[g][i] = (r0 + r1) + (r2 + r3);
            __syncthreads();
            const float r = part_r[0][i] + part_r[1][i] + part_r[2][i] + part_r[3][i];
            const float ax = row[192 + i];
            const float v  = row[64 + i];
            const float alpha = 1.f / (1.f + __expf(-(ax + da * r + ba)));
            const float cvk = (1.f - alpha) * v;
            float o0 = 0.f, o1 = 0.f, o2 = 0.f, o3 = 0.f;
            #pragma unroll
            for (int jj = 0; jj < 16; jj += 4) {
                s[jj]     = alpha * s[jj]     + cvk * row[g * 16 + jj];
                s[jj + 1] = alpha * s[jj + 1] + cvk * row[g * 16 + jj + 1];
                s[jj + 2] = alpha * s[jj + 2] + cvk * row[g * 16 + jj + 2];
                s[jj + 3] = alpha * s[jj + 3] + cvk * row[g * 16 + jj + 3];
                o0 += s[jj]     * row[128 + g * 16 + jj];
                o1 += s[jj + 1] * row[128 + g * 16 + jj + 1];
                o2 += s[jj + 2] * row[128 + g * 16 + jj + 2];
                o3 += s[jj + 3] * row[128 + g * 16 + jj + 3];
            }
            part_o[g][i] = (o0 + o1) + (o2 + o3);
            __syncthreads();
            if (g == 0) {
                const float o = part_o[0][i] + part_o[1][i] + part_o[2][i] + part_o[3][i];
                const float sig = 1.f / (1.f + __expf(-o));
                cell[(size_t)(b * T_LEN + t) * NS + i] = __float2bfloat16(o * o * sig);
            }
        }
    }
    #pragma unroll
    for (int jj = 0; jj < 16; jj++)
        Sout[(size_t)b * 4096 + i * 64 + g * 16 + jj] = s[jj];
}

extern "C" void kernel_launch(void* const* d_in, const int* in_sizes, int n_in,
                              void* d_out, int out_size, void* d_ws, size_t ws_size,
                              hipStream_t stream) {
    const float* x     = (const float*)d_in[0];   // [32768, 1024] f32
    const float* W_in  = (const float*)d_in[1];   // [1024, 1024]
    const float* W_k   = (const float*)d_in[2];   // [64, 1024]
    const float* W_v   = (const float*)d_in[3];
    const float* W_q   = (const float*)d_in[4];
    const float* W_a   = (const float*)d_in[5];
    const float* d_alpha = (const float*)d_in[6]; // [64]
    const float* b_alpha = (const float*)d_in[7]; // [64]
    const float* W_out = (const float*)d_in[8];   // [1024, 64]

    char* ws = (char*)d_ws;
    u16*   xp     = (u16*)ws;                               // [0, 64MB)  bf16 32768x1024
    float* P      = (float*)(ws + (size_t)67108864);        // [64MB, 96MB) f32 32768x256
    u16*   Win16  = (u16*)(ws + (size_t)100663296);         // 2MB
    u16*   Wc16   = (u16*)(ws + (size_t)102760448);         // 512KB
    u16*   Wout16 = (u16*)(ws + (size_t)103284736);         // 128KB
    __hip_bfloat16* cell = (__hip_bfloat16*)ws;             // overlay [0,4MB): xp dead after P-proj

    float* out  = (float*)d_out;                  // [32768,1024] f32
    float* Sout = out + (size_t)32768 * 1024;     // [16,64,64] f32

    convert_w<<<dim3(5376), dim3(256), 0, stream>>>(W_in, W_k, W_v, W_q, W_a, W_out,
                                                    Win16, Wc16, Wout16);
    // xp = silu(x @ W_in^T), bf16
    gemm_bt<1, 1><<<dim3(256, 8), dim3(256), 0, stream>>>((const void*)x, Win16, (void*)xp,
                                                          32768, 1024, 1024);
    // P = xp @ Wc^T  (k|v|q|ax), f32
    gemm_bt<0, 0><<<dim3(256, 2), dim3(256), 0, stream>>>((const void*)xp, Wc16, (void*)P,
                                                          32768, 256, 1024);
    // sequential gated scan -> cell (bf16), Sout (f32)
    scan_kernel<<<dim3(16), dim3(256), 0, stream>>>(P, d_alpha, b_alpha, cell, Sout);
    // out = cell @ W_out^T, f32
    gemm_bt<0, 0><<<dim3(256, 8), dim3(256), 0, stream>>>((const void*)cell, Wout16, (void*)out,
                                                          32768, 1024, 64);
}

// Round 4
// 1168.624 us; speedup vs baseline: 1.3451x; 1.3451x over previous
//
#include <hip/hip_runtime.h>
#include <hip/hip_bf16.h>

typedef unsigned short u16;
typedef __bf16 bf16x8 __attribute__((ext_vector_type(8)));
typedef float f32x4 __attribute__((ext_vector_type(4)));

__device__ inline u16 f2b(float f) {
    __hip_bfloat16 h = __float2bfloat16(f);
    return *(u16*)&h;
}

#define BM 128
#define BN 128
#define BK 32
#define LDSS 40  // 32 + 8 pad shorts per row

// C[M,N] = A[M,K] * W[N,K]^T.  W is bf16 (pre-converted), row-major K-contiguous.
// A: AF32=1 -> float32 (converted to bf16 during LDS staging), AF32=0 -> bf16.
// EPI: 0 = store f32, 1 = silu -> bf16
template<int AF32, int EPI>
__global__ __launch_bounds__(256) void gemm_bt(const void* __restrict__ Av,
                                               const u16* __restrict__ W,
                                               void* __restrict__ Cv,
                                               int M, int N, int K) {
    __shared__ u16 lds_a[BM * LDSS];
    __shared__ u16 lds_b[BN * LDSS];
    const int tid  = threadIdx.x;
    const int wave = tid >> 6;
    const int lane = tid & 63;
    const int wr = wave >> 1, wc = wave & 1;   // 2x2 wave grid, 64x64 each
    const int quad = lane >> 4, l15 = lane & 15;
    const int bm = blockIdx.x * BM;
    const int bn = blockIdx.y * BN;

    f32x4 acc[4][4] = {};

    const int lrow = tid >> 2;    // 0..63
    const int lch  = tid & 3;     // 16B chunk within 32-k bf16 row

    for (int k0 = 0; k0 < K; k0 += BK) {
        __syncthreads();
        if (AF32) {
            const float* Af = (const float*)Av;
            const int srow = tid >> 3;   // 0..31
            const int sch  = tid & 7;    // float4 chunk within 32-k f32 row
            #pragma unroll
            for (int p = 0; p < 4; ++p) {
                const int r = p * 32 + srow;
                float4 va = *(const float4*)&Af[(size_t)(bm + r) * K + k0 + sch * 4];
                ushort4 pk = make_ushort4(f2b(va.x), f2b(va.y), f2b(va.z), f2b(va.w));
                *(ushort4*)&lds_a[r * LDSS + sch * 4] = pk;
            }
        } else {
            const u16* Ab = (const u16*)Av;
            *(uint4*)&lds_a[lrow * LDSS + lch * 8] =
                *(const uint4*)&Ab[(size_t)(bm + lrow) * K + k0 + lch * 8];
            *(uint4*)&lds_a[(lrow + 64) * LDSS + lch * 8] =
                *(const uint4*)&Ab[(size_t)(bm + lrow + 64) * K + k0 + lch * 8];
        }
        *(uint4*)&lds_b[lrow * LDSS + lch * 8] =
            *(const uint4*)&W[(size_t)(bn + lrow) * K + k0 + lch * 8];
        *(uint4*)&lds_b[(lrow + 64) * LDSS + lch * 8] =
            *(const uint4*)&W[(size_t)(bn + lrow + 64) * K + k0 + lch * 8];
        __syncthreads();

        bf16x8 af[4], bf[4];
        #pragma unroll
        for (int i = 0; i < 4; i++)
            af[i] = *(const bf16x8*)&lds_a[(wr * 64 + i * 16 + l15) * LDSS + quad * 8];
        #pragma unroll
        for (int j = 0; j < 4; j++)
            bf[j] = *(const bf16x8*)&lds_b[(wc * 64 + j * 16 + l15) * LDSS + quad * 8];
        #pragma unroll
        for (int i = 0; i < 4; i++)
            #pragma unroll
            for (int j = 0; j < 4; j++)
                acc[i][j] = __builtin_amdgcn_mfma_f32_16x16x32_bf16(af[i], bf[j], acc[i][j], 0, 0, 0);
    }

    #pragma unroll
    for (int i = 0; i < 4; i++) {
        #pragma unroll
        for (int j = 0; j < 4; j++) {
            #pragma unroll
            for (int r = 0; r < 4; r++) {
                const int row = bm + wr * 64 + i * 16 + quad * 4 + r;
                const int col = bn + wc * 64 + j * 16 + l15;
                float v = acc[i][j][r];
                if (EPI == 1) {
                    v = v / (1.f + __expf(-v));   // silu
                    ((__hip_bfloat16*)Cv)[(size_t)row * N + col] = __float2bfloat16(v);
                } else {
                    ((float*)Cv)[(size_t)row * N + col] = v;
                }
            }
        }
    }
}

// Convert all weights f32 -> bf16: W_in [1024x1024], concat(W_k,W_v,W_q,W_a) [256x1024], W_out [1024x64]
__global__ __launch_bounds__(256) void convert_w(const float* __restrict__ Win,
                                                 const float* __restrict__ Wk,
                                                 const float* __restrict__ Wv,
                                                 const float* __restrict__ Wq,
                                                 const float* __restrict__ Wa,
                                                 const float* __restrict__ Wout,
                                                 u16* __restrict__ Win16,
                                                 u16* __restrict__ Wc16,
                                                 u16* __restrict__ Wout16) {
    int idx = blockIdx.x * 256 + threadIdx.x;   // 0 .. 1376255
    if (idx < 1048576) { Win16[idx] = f2b(Win[idx]); return; }
    int i2 = idx - 1048576;
    if (i2 < 262144) {
        int which = i2 >> 16;
        int off = i2 & 65535;
        const float* s = (which == 0) ? Wk : (which == 1) ? Wv : (which == 2) ? Wq : Wa;
        Wc16[i2] = f2b(s[off]);
        return;
    }
    int i3 = i2 - 262144;
    Wout16[i3] = f2b(Wout[i3]);
}

#define T_LEN 2048
#define NS 64

// Barrier-free scan. Grid: 128 blocks (16 batches x 8 row-groups), 64 threads (1 wave).
// lane = c*8 + r: wave owns rows i = 8w..8w+7 (r), each lane covers cols [8c, 8c+8).
// State s[8] in VGPRs. Cross-chunk sums via __shfl_xor(8/16/32). Register ring
// buffer prefetches P rows 4 steps ahead (covers L3 latency).
__global__ __launch_bounds__(64) void scan_kernel(const float* __restrict__ P,
                                                  const float* __restrict__ d_alpha,
                                                  const float* __restrict__ b_alpha,
                                                  __hip_bfloat16* __restrict__ cell,
                                                  float* __restrict__ Sout) {
    const int blk = blockIdx.x;
    const int b = blk >> 3;
    const int w = blk & 7;
    const int lane = threadIdx.x;
    const int c = lane >> 3;        // col chunk 0..7
    const int r = lane & 7;         // row-in-group 0..7
    const int i = w * 8 + r;        // state row 0..63
    const int kc = c * 8;           // col base

    const float da = d_alpha[i];
    const float ba = b_alpha[i];
    const float* Pb = P + (size_t)b * T_LEN * 256;

    float s[8];
    #pragma unroll
    for (int j = 0; j < 8; j++) s[j] = 0.f;

    // ring buffers: 4 phases
    float4 ka[4], kb[4], qa[4], qb[4];
    float  vv[4], aa[4];

    #pragma unroll
    for (int p = 0; p < 4; ++p) {
        const float* row = &Pb[(size_t)p * 256];
        ka[p] = *(const float4*)&row[kc];
        kb[p] = *(const float4*)&row[kc + 4];
        qa[p] = *(const float4*)&row[128 + kc];
        qb[p] = *(const float4*)&row[128 + kc + 4];
        vv[p] = row[64 + i];
        aa[p] = row[192 + i];
    }

    for (int t0 = 0; t0 < T_LEN; t0 += 4) {
        #pragma unroll
        for (int p = 0; p < 4; ++p) {
            const int t = t0 + p;
            const float4 k0 = ka[p], k1 = kb[p];
            const float4 q0 = qa[p], q1 = qb[p];
            const float v = vv[p], ax = aa[p];

            // prefetch t+4 into this phase's slot
            {
                int tn = t + 4; if (tn > T_LEN - 1) tn = T_LEN - 1;
                const float* row = &Pb[(size_t)tn * 256];
                ka[p] = *(const float4*)&row[kc];
                kb[p] = *(const float4*)&row[kc + 4];
                qa[p] = *(const float4*)&row[128 + kc];
                qb[p] = *(const float4*)&row[128 + kc + 4];
                vv[p] = row[64 + i];
                aa[p] = row[192 + i];
            }

            // retrieved partial: s . k (this lane's 8 cols)
            float rp = s[0]*k0.x + s[1]*k0.y + s[2]*k0.z + s[3]*k0.w
                     + s[4]*k1.x + s[5]*k1.y + s[6]*k1.z + s[7]*k1.w;
            rp += __shfl_xor(rp, 8);
            rp += __shfl_xor(rp, 16);
            rp += __shfl_xor(rp, 32);

            const float alpha = 1.f / (1.f + __expf(-(ax + da * rp + ba)));
            const float cvk = (1.f - alpha) * v;

            s[0] = alpha * s[0] + cvk * k0.x;
            s[1] = alpha * s[1] + cvk * k0.y;
            s[2] = alpha * s[2] + cvk * k0.z;
            s[3] = alpha * s[3] + cvk * k0.w;
            s[4] = alpha * s[4] + cvk * k1.x;
            s[5] = alpha * s[5] + cvk * k1.y;
            s[6] = alpha * s[6] + cvk * k1.z;
            s[7] = alpha * s[7] + cvk * k1.w;

            float op = s[0]*q0.x + s[1]*q0.y + s[2]*q0.z + s[3]*q0.w
                     + s[4]*q1.x + s[5]*q1.y + s[6]*q1.z + s[7]*q1.w;
            op += __shfl_xor(op, 8);
            op += __shfl_xor(op, 16);
            op += __shfl_xor(op, 32);

            const float sig = 1.f / (1.f + __expf(-op));
            const float o = op * op * sig;
            if (c == 0)
                cell[(size_t)(b * T_LEN + t) * NS + i] = __float2bfloat16(o);
        }
    }

    // final state
    float4 s0 = make_float4(s[0], s[1], s[2], s[3]);
    float4 s1 = make_float4(s[4], s[5], s[6], s[7]);
    *(float4*)&Sout[(size_t)b * 4096 + i * 64 + kc]     = s0;
    *(float4*)&Sout[(size_t)b * 4096 + i * 64 + kc + 4] = s1;
}

extern "C" void kernel_launch(void* const* d_in, const int* in_sizes, int n_in,
                              void* d_out, int out_size, void* d_ws, size_t ws_size,
                              hipStream_t stream) {
    const float* x     = (const float*)d_in[0];   // [32768, 1024] f32
    const float* W_in  = (const float*)d_in[1];   // [1024, 1024]
    const float* W_k   = (const float*)d_in[2];   // [64, 1024]
    const float* W_v   = (const float*)d_in[3];
    const float* W_q   = (const float*)d_in[4];
    const float* W_a   = (const float*)d_in[5];
    const float* d_alpha = (const float*)d_in[6]; // [64]
    const float* b_alpha = (const float*)d_in[7]; // [64]
    const float* W_out = (const float*)d_in[8];   // [1024, 64]

    char* ws = (char*)d_ws;
    u16*   xp     = (u16*)ws;                               // [0, 64MB)  bf16 32768x1024
    float* P      = (float*)(ws + (size_t)67108864);        // [64MB, 96MB) f32 32768x256
    u16*   Win16  = (u16*)(ws + (size_t)100663296);         // 2MB
    u16*   Wc16   = (u16*)(ws + (size_t)102760448);         // 512KB
    u16*   Wout16 = (u16*)(ws + (size_t)103284736);         // 128KB
    __hip_bfloat16* cell = (__hip_bfloat16*)ws;             // overlay [0,4MB): xp dead after P-proj

    float* out  = (float*)d_out;                  // [32768,1024] f32
    float* Sout = out + (size_t)32768 * 1024;     // [16,64,64] f32

    convert_w<<<dim3(5376), dim3(256), 0, stream>>>(W_in, W_k, W_v, W_q, W_a, W_out,
                                                    Win16, Wc16, Wout16);
    // xp = silu(x @ W_in^T), bf16
    gemm_bt<1, 1><<<dim3(256, 8), dim3(256), 0, stream>>>((const void*)x, Win16, (void*)xp,
                                                          32768, 1024, 1024);
    // P = xp @ Wc^T  (k|v|q|ax), f32
    gemm_bt<0, 0><<<dim3(256, 2), dim3(256), 0, stream>>>((const void*)xp, Wc16, (void*)P,
                                                          32768, 256, 1024);
    // barrier-free sequential gated scan -> cell (bf16), Sout (f32)
    scan_kernel<<<dim3(128), dim3(64), 0, stream>>>(P, d_alpha, b_alpha, cell, Sout);
    // out = cell @ W_out^T, f32
    gemm_bt<0, 0><<<dim3(256, 8), dim3(256), 0, stream>>>((const void*)cell, Wout16, (void*)out,
                                                          32768, 1024, 64);
}